// Round 1
// baseline (252.405 us; speedup 1.0000x reference)
//
#include <hip/hip_runtime.h>
#include <hip/hip_fp16.h>
#include <stdint.h>

// Problem dims (fixed by reference)
// Reference dtypes: x fp16, bias fp16, out fp16 -> harness passes/reads FLOAT32.
// packed_w int32 (8192 x 512), 16 two-bit codes per word, values {0,1,3}.
#define M_DIM 1024
#define N_DIM 8192
#define K_DIM 8192
#define KP    (K_DIM / 16)   // 512 packed int32 words per weight row

#define BM 128
#define BN 128
#define BK 64
#define NTHREADS 256
#define B_STRIDE 144          // fallback kernel only

// Transposed A workspace layout (bytes), built by cvt_x_t:
//   mt(8):2 MiB | kt(128):16 KiB | i32(4):4 KiB | ks(4):1 KiB | q(2):512 | r(32):16
// A-fragment (i32, ks) = contiguous 1 KB at base + lane*16 (lane = q*32+r).
#define MT_STRIDE 2097152
#define KT_STRIDE 16384

typedef _Float16 half8   __attribute__((ext_vector_type(8)));
typedef __fp16   fp16x2  __attribute__((ext_vector_type(2)));
typedef float    f32x4   __attribute__((ext_vector_type(4)));
typedef float    f32x16  __attribute__((ext_vector_type(16)));

__device__ __forceinline__ uint32_t cvt2(float a, float b) {
  fp16x2 p = __builtin_amdgcn_cvt_pkrtz(a, b);   // RTZ exact: values are fp16-representable
  return __builtin_bit_cast(uint32_t, p);
}

// ---- consumer-side half-word ternary decode ----
// word = 16 codes; quad half (sh = quad*16) = 8 codes -> half8 MFMA B-fragment.
// h bytes [h1,h0]; U0 = h&0x3333 -> bytes [c4|c6<<4, c0|c2<<4]; U1<<16 = [c5|c7<<4, c1|c3<<4]<<16.
// W = U0 | (h<<14 & 0x33330000) -> bytes [c5|c7<<4, c4|c6<<4, c1|c3<<4, c0|c2<<4].
// comb0 = W.b0 | W.b2<<8 -> spread -> sel [c0,c1,c2,c3]; comb1 = W.b1 | W.b3<<8 -> [c4..c7].
// T byte-table [0x00,0x3C,0x06,0x42] = fp16 hi-bytes of {0,1,2,3} (low byte always 0).
__device__ __forceinline__ half8 dec_frag(uint32_t word, uint32_t sh) {
  const uint32_t T = 0x42063C00u;
  uint32_t h  = (word >> sh) & 0xFFFFu;
  uint32_t W  = (h & 0x3333u) | ((h << 14) & 0x33330000u);
  uint32_t c0 = __builtin_amdgcn_perm(0u, W, 0x04040200u);  // W.b0 | W.b2<<8
  uint32_t c1 = __builtin_amdgcn_perm(0u, W, 0x04040301u);  // W.b1 | W.b3<<8
  uint32_t s0 = (c0 * 0x1001u) & 0x03030303u;               // [c0,c1,c2,c3]
  uint32_t s1 = (c1 * 0x1001u) & 0x03030303u;               // [c4,c5,c6,c7]
  uint32_t P0 = __builtin_amdgcn_perm(0u, T, s0);
  uint32_t P1 = __builtin_amdgcn_perm(0u, T, s1);
  uint4 v;
  v.x = __builtin_amdgcn_perm(P0, 0u, 0x05000400u);  // fp16(c0), fp16(c1)
  v.y = __builtin_amdgcn_perm(P0, 0u, 0x07000600u);  // fp16(c2), fp16(c3)
  v.z = __builtin_amdgcn_perm(P1, 0u, 0x05000400u);  // fp16(c4), fp16(c5)
  v.w = __builtin_amdgcn_perm(P1, 0u, 0x07000600u);  // fp16(c6), fp16(c7)
  return __builtin_bit_cast(half8, v);
}

// ---- pre-pass: x f32 -> fp16, transposed-tiled into workspace (R8, verified) ----
__global__ __launch_bounds__(256)
void cvt_x_t(const float* __restrict__ x, char* __restrict__ xhT) {
  __shared__ __align__(16) char st[16384];
  const int b  = blockIdx.x;
  const int mt = b >> 7, kt = b & 127;
  const int t  = threadIdx.x;
#pragma unroll
  for (int p = 0; p < 8; ++p) {
    int f   = t + 256 * p;
    int R   = f >> 4;
    int cc4 = f & 15;
    float4 v = *(const float4*)(x + (size_t)(mt * 128 + R) * K_DIM + kt * 64 + cc4 * 4);
    uint32_t w0 = cvt2(v.x, v.y), w1 = cvt2(v.z, v.w);
    int c8 = cc4 >> 1, hh = cc4 & 1;
    int i32 = R >> 5, r = R & 31, ks = c8 >> 1, q = c8 & 1;
    *(uint2*)(st + i32 * 4096 + ks * 1024 + q * 512 + r * 16 + hh * 8) = make_uint2(w0, w1);
  }
  __syncthreads();
  char* outb = xhT + (size_t)mt * MT_STRIDE + (size_t)kt * KT_STRIDE;
#pragma unroll
  for (int e = 0; e < 4; ++e) {
    int d = (e * 256 + t) * 16;
    *(uint4*)(outb + d) = *(const uint4*)(st + d);
  }
}

// ====== fast path: A in regs, B raw-word LDS stage (2 KB dbuf) + decode-at-consumer ======
// R9: wave tile 64x64 (m2n2) -> 128x32 (m4n1). Each decoded B-fragment now feeds
// 4 MFMAs (was 2); per-block decode work is minimal (each word-half decoded once).
// A-tile (16 KB/step) is read identically by all 4 waves -> L1 serves 4x reuse,
// unique per-block A traffic unchanged.
__global__ __launch_bounds__(NTHREADS, 2)
void ternary_gemm_dc(const char* __restrict__ xhT,
                     const int*  __restrict__ pw,
                     const float* __restrict__ bias,
                     float*       __restrict__ out) {
  __shared__ __align__(16) char stg[2 * 2048];   // raw packed words: 128 rows x int4, dbuf

  const int tid  = threadIdx.x;
  const int lane = tid & 63;
  const int w    = tid >> 6;          // 0..3 = N-quarter of the block tile
  const int bid  = blockIdx.x;
  const int mt   = bid & 7;           // XCD swizzle: one 2 MiB A-slab per XCD hot in L2
  const int bm   = mt * BM;
  const int bn   = (bid >> 3) * BN;

  // A register-load pointers (transposed ws): i -> 32-row group i of the mt slab
  const char* pA[4];
#pragma unroll
  for (int i = 0; i < 4; ++i)
    pA[i] = xhT + (size_t)mt * MT_STRIDE + i * 4096 + lane * 16;

  // Word staging: thread t -> row t>>1, word-pair t&1 (int2, coalesced global load)
  const int rT = tid >> 1, hT = tid & 1;
  const int2* gB = (const int2*)pw + (size_t)(bn + rT) * (KP / 2) + hT;
  const int stOff = rT * 16 + hT * 8;

  // Consumer row: this wave's 32 N-columns = W-rows w*32 + (lane&31)
  const int rowOff = (w * 32 + (lane & 31)) * 16;
  const uint32_t sh = (lane >> 5) * 16;   // quad selects codes 0-7 vs 8-15 of each word

  f32x16 acc[4];
#pragma unroll
  for (int i = 0; i < 4; ++i) acc[i] = (f32x16)(0.f);

  const int NT = K_DIM / BK;   // 128

  // ---- prologue: words(tile0)->stg[0]; A(tile0)->regs; words(tile1)->regs ----
  *(int2*)(stg + stOff) = gB[0];
  half8 aA[4][4], aB[4][4];
#pragma unroll
  for (int i = 0; i < 4; ++i)
#pragma unroll
    for (int ks = 0; ks < 4; ++ks)
      aA[i][ks] = *(const half8*)(pA[i] + ks * 1024);
#pragma unroll
  for (int i = 0; i < 4; ++i) pA[i] += KT_STRIDE;   // -> tile 1
  int2 wcur = gB[2];                                 // tile 1 words
  __syncthreads();

  auto step = [&](half8 (&aC)[4][4], half8 (&aN)[4][4], int cur, int kt) {
    // Prefetch A(kt+1) into the other register set (consumed next step)
#pragma unroll
    for (int i = 0; i < 4; ++i)
#pragma unroll
      for (int ks = 0; ks < 4; ++ks)
        aN[i][ks] = *(const half8*)(pA[i] + ks * 1024);
    if (kt < NT - 2) {
#pragma unroll
      for (int i = 0; i < 4; ++i) pA[i] += KT_STRIDE;
    }
    int kn2 = (kt + 2 < NT) ? (kt + 2) : (NT - 1);
    int2 wnxt = gB[kn2 * 2];

    // Read this tile's raw words (1 row x int4); write next tile's words to other buffer
    uint32_t wr[4];
    *(uint4*)wr = *(const uint4*)(stg + cur * 2048 + rowOff);
    *(int2*)(stg + (cur ^ 1) * 2048 + stOff) = wcur;

    // Compute: decode one fragment per ks, feed all 4 M-position MFMAs
#pragma unroll
    for (int ks = 0; ks < 4; ++ks) {
      half8 bf = dec_frag(wr[ks], sh);
      acc[0] = __builtin_amdgcn_mfma_f32_32x32x16_f16(aC[0][ks], bf, acc[0], 0, 0, 0);
      acc[1] = __builtin_amdgcn_mfma_f32_32x32x16_f16(aC[1][ks], bf, acc[1], 0, 0, 0);
      acc[2] = __builtin_amdgcn_mfma_f32_32x32x16_f16(aC[2][ks], bf, acc[2], 0, 0, 0);
      acc[3] = __builtin_amdgcn_mfma_f32_32x32x16_f16(aC[3][ks], bf, acc[3], 0, 0, 0);
    }

    __syncthreads();   // single barrier: word-writes(kt+1) visible; word-reads(kt) done
    wcur = wnxt;
  };

  for (int kt = 0; kt < NT; kt += 2) {   // 2x unrolled: A-register ping-pong without copies
    step(aA, aB, 0, kt);
    step(aB, aA, 1, kt + 1);
  }

  // Epilogue: 32x32 C/D (m74/m101): col(n)=lane&31, row(m)=(reg&3)+8*(reg>>2)+4*(lane>>5)
  // fp16 rounding replicated exactly: f16(y) + f16(bias) in half, widen to f32.
  {
    int n = bn + w * 32 + (lane & 31);
    __half hb = __float2half_rn(bias[n]);
#pragma unroll
    for (int i = 0; i < 4; ++i) {
      int mbase = bm + i * 32 + 4 * (lane >> 5);
#pragma unroll
      for (int reg = 0; reg < 16; ++reg) {
        int m = mbase + (reg & 3) + 8 * (reg >> 2);
        __half hy = __float2half_rn(acc[i][reg]);
        out[(size_t)m * N_DIM + n] = __half2float(__hadd(hy, hb));
      }
    }
  }
}

// ================= fallback (R4 kernel, known-good): used only if ws too small =================
__device__ __forceinline__ uint32_t unpack_pair16(uint32_t u, int p) {
  uint32_t c0 = (u >> (4 * p)) & 3u;
  uint32_t c1 = (u >> (4 * p + 2)) & 3u;
  uint32_t lo = (c0 & 1u) * 0x3C00u + (c0 >> 1) * 0x0600u;
  uint32_t hi = (c1 & 1u) * 0x3C00u + (c1 >> 1) * 0x0600u;
  return lo | (hi << 16);
}

__global__ __launch_bounds__(NTHREADS, 2)
void ternary_gemm(const float* __restrict__ x,
                  const int*   __restrict__ pw,
                  const float* __restrict__ bias,
                  float*       __restrict__ out) {
  __shared__ __align__(16) char AsB[128 * B_STRIDE];
  __shared__ __align__(16) char BsB[128 * B_STRIDE];

  const int tid  = threadIdx.x;
  const int lane = tid & 63;
  const int w    = tid >> 6;
  const int wm   = w >> 1, wn = w & 1;
  const int bid  = blockIdx.x;
  const int bm   = (bid & 7) * 128;
  const int bn   = (bid >> 3) * 128;

  const int rT = tid >> 1, hT = tid & 1;
  const float* gA = x + (size_t)(bm + rT) * K_DIM + hT * 32;
  char* const  lA = AsB + rT * B_STRIDE + hT * 64;
  const int2* gB = (const int2*)pw + (size_t)(bn + rT) * (KP / 2) + hT;
  char* dBp[4];
#pragma unroll
  for (int h = 0; h < 4; ++h)
    dBp[h] = BsB + rT * B_STRIDE + (hT * 4 + h) * 16;

  int offA[4][2], offB[4][2];
#pragma unroll
  for (int i = 0; i < 4; ++i)
#pragma unroll
    for (int ks = 0; ks < 2; ++ks) {
      int c = ks * 4 + (lane >> 4);
      offA[i][ks] = (wm * 64 + i * 16 + (lane & 15)) * B_STRIDE + c * 16;
      offB[i][ks] = (wn * 64 + i * 16 + (lane & 15)) * B_STRIDE + c * 16;
    }

  f32x4 acc[4][4];
#pragma unroll
  for (int i = 0; i < 4; ++i)
#pragma unroll
    for (int j = 0; j < 4; ++j)
      acc[i][j] = (f32x4){0.f, 0.f, 0.f, 0.f};

  const int NT = K_DIM / BK;
  for (int kt = 0; kt < NT; ++kt) {
    __syncthreads();
    int2 wcur = gB[kt * 2];
    float4 av[8];
#pragma unroll
    for (int v = 0; v < 8; ++v) av[v] = *(const float4*)(gA + kt * BK + v * 4);
    uint32_t d0[8], d1[8];
#pragma unroll
    for (int p = 0; p < 8; ++p) d0[p] = unpack_pair16((uint32_t)wcur.x, p);
#pragma unroll
    for (int p = 0; p < 8; ++p) d1[p] = unpack_pair16((uint32_t)wcur.y, p);
    *(uint4*)dBp[0] = make_uint4(d0[0], d0[1], d0[2], d0[3]);
    *(uint4*)dBp[1] = make_uint4(d0[4], d0[5], d0[6], d0[7]);
    *(uint4*)dBp[2] = make_uint4(d1[0], d1[1], d1[2], d1[3]);
    *(uint4*)dBp[3] = make_uint4(d1[4], d1[5], d1[6], d1[7]);
#pragma unroll
    for (int v = 0; v < 4; ++v) {
      uint4 aw;
      aw.x = cvt2(av[2 * v].x, av[2 * v].y);
      aw.y = cvt2(av[2 * v].z, av[2 * v].w);
      aw.z = cvt2(av[2 * v + 1].x, av[2 * v + 1].y);
      aw.w = cvt2(av[2 * v + 1].z, av[2 * v + 1].w);
      *(uint4*)(lA + v * 16) = aw;
    }
    __syncthreads();
#pragma unroll
    for (int ks = 0; ks < 2; ++ks) {
      half8 af[4], bf[4];
#pragma unroll
      for (int i = 0; i < 4; ++i) af[i] = *(const half8*)(AsB + offA[i][ks]);
#pragma unroll
      for (int j = 0; j < 4; ++j) bf[j] = *(const half8*)(BsB + offB[j][ks]);
#pragma unroll
      for (int i = 0; i < 4; ++i)
#pragma unroll
        for (int j = 0; j < 4; ++j)
          acc[i][j] = __builtin_amdgcn_mfma_f32_16x16x32_f16(af[i], bf[j], acc[i][j], 0, 0, 0);
    }
  }
#pragma unroll
  for (int j = 0; j < 4; ++j) {
    int n = bn + wn * 64 + j * 16 + (lane & 15);
    __half hb = __float2half_rn(bias[n]);
#pragma unroll
    for (int i = 0; i < 4; ++i) {
      int m0 = bm + wm * 64 + i * 16 + (lane >> 4) * 4;
#pragma unroll
      for (int r = 0; r < 4; ++r) {
        __half hy = __float2half_rn(acc[i][j][r]);
        out[(size_t)(m0 + r) * N_DIM + n] = __half2float(__hadd(hy, hb));
      }
    }
  }
}

extern "C" void kernel_launch(void* const* d_in, const int* in_sizes, int n_in,
                              void* d_out, int out_size, void* d_ws, size_t ws_size,
                              hipStream_t stream) {
  (void)in_sizes; (void)n_in; (void)out_size;
  const float* x    = (const float*)d_in[0];
  const int*   pwp  = (const int*)d_in[1];
  const float* bias = (const float*)d_in[2];
  float*       outp = (float*)d_out;

  const size_t need = (size_t)M_DIM * K_DIM * 2;   // 16 MiB fp16 x (transposed)
  if (ws_size >= need) {
    char* xhT = (char*)d_ws;
    cvt_x_t<<<8 * 128, 256, 0, stream>>>(x, xhT);
    dim3 grid((M_DIM / BM) * (N_DIM / BN));        // 512 blocks
    ternary_gemm_dc<<<grid, NTHREADS, 0, stream>>>(xhT, pwp, bias, outp);
  } else {
    dim3 grid((M_DIM / 128) * (N_DIM / 128));      // 512 blocks
    ternary_gemm<<<grid, NTHREADS, 0, stream>>>(x, pwp, bias, outp);
  }
}

// Round 2
// 240.473 us; speedup vs baseline: 1.0496x; 1.0496x over previous
//
#include <hip/hip_runtime.h>
#include <hip/hip_fp16.h>
#include <stdint.h>

// Problem dims (fixed by reference)
// Reference dtypes: x fp16, bias fp16, out fp16 -> harness passes/reads FLOAT32.
// packed_w int32 (8192 x 512), 16 two-bit codes per word, values {0,1,3}.
#define M_DIM 1024
#define N_DIM 8192
#define K_DIM 8192
#define KP    (K_DIM / 16)   // 512 packed int32 words per weight row

#define BM 128
#define BN 128
#define BK 64
#define NTHREADS 256
#define B_STRIDE 144          // fallback kernel only

// Transposed A workspace layout (bytes), built by cvt_x_t:
//   mt(8):2 MiB | kt(128):16 KiB | i32(4):4 KiB | ks(4):1 KiB | q(2):512 | r(32):16
// A-fragment (i32, ks) = contiguous 1 KB at base + lane*16 (lane = q*32+r).
#define MT_STRIDE 2097152
#define KT_STRIDE 16384

typedef _Float16 half8   __attribute__((ext_vector_type(8)));
typedef __fp16   fp16x2  __attribute__((ext_vector_type(2)));
typedef float    f32x4   __attribute__((ext_vector_type(4)));
typedef float    f32x16  __attribute__((ext_vector_type(16)));

__device__ __forceinline__ uint32_t cvt2(float a, float b) {
  fp16x2 p = __builtin_amdgcn_cvt_pkrtz(a, b);   // RTZ exact: values are fp16-representable
  return __builtin_bit_cast(uint32_t, p);
}

// Async global->LDS 16B copy. LDS dest is wave-uniform base + lane*16 (HW rule),
// so the LDS base passed here must be wave-uniform and the global ptr per-lane.
__device__ __forceinline__ void gload_lds16(const char* g, char* l) {
  __builtin_amdgcn_global_load_lds(
      (const __attribute__((address_space(1))) void*)g,
      (__attribute__((address_space(3))) void*)l, 16, 0, 0);
}

// ---- consumer-side half-word ternary decode (verified R8) ----
// word = 16 codes; quad half (sh = quad*16) = 8 codes -> half8 MFMA B-fragment.
// T byte-table [0x00,0x3C,0x06,0x42] = fp16 hi-bytes of {0,1,2,3} (low byte always 0).
__device__ __forceinline__ half8 dec_frag(uint32_t word, uint32_t sh) {
  const uint32_t T = 0x42063C00u;
  uint32_t h  = (word >> sh) & 0xFFFFu;
  uint32_t W  = (h & 0x3333u) | ((h << 14) & 0x33330000u);
  uint32_t c0 = __builtin_amdgcn_perm(0u, W, 0x04040200u);  // W.b0 | W.b2<<8
  uint32_t c1 = __builtin_amdgcn_perm(0u, W, 0x04040301u);  // W.b1 | W.b3<<8
  uint32_t s0 = (c0 * 0x1001u) & 0x03030303u;               // [c0,c1,c2,c3]
  uint32_t s1 = (c1 * 0x1001u) & 0x03030303u;               // [c4,c5,c6,c7]
  uint32_t P0 = __builtin_amdgcn_perm(0u, T, s0);
  uint32_t P1 = __builtin_amdgcn_perm(0u, T, s1);
  uint4 v;
  v.x = __builtin_amdgcn_perm(P0, 0u, 0x05000400u);  // fp16(c0), fp16(c1)
  v.y = __builtin_amdgcn_perm(P0, 0u, 0x07000600u);  // fp16(c2), fp16(c3)
  v.z = __builtin_amdgcn_perm(P1, 0u, 0x05000400u);  // fp16(c4), fp16(c5)
  v.w = __builtin_amdgcn_perm(P1, 0u, 0x07000600u);  // fp16(c6), fp16(c7)
  return __builtin_bit_cast(half8, v);
}

// ---- pre-pass: x f32 -> fp16, transposed-tiled into workspace (R8, verified) ----
__global__ __launch_bounds__(256)
void cvt_x_t(const float* __restrict__ x, char* __restrict__ xhT) {
  __shared__ __align__(16) char st[16384];
  const int b  = blockIdx.x;
  const int mt = b >> 7, kt = b & 127;
  const int t  = threadIdx.x;
#pragma unroll
  for (int p = 0; p < 8; ++p) {
    int f   = t + 256 * p;
    int R   = f >> 4;
    int cc4 = f & 15;
    float4 v = *(const float4*)(x + (size_t)(mt * 128 + R) * K_DIM + kt * 64 + cc4 * 4);
    uint32_t w0 = cvt2(v.x, v.y), w1 = cvt2(v.z, v.w);
    int c8 = cc4 >> 1, hh = cc4 & 1;
    int i32 = R >> 5, r = R & 31, ks = c8 >> 1, q = c8 & 1;
    *(uint2*)(st + i32 * 4096 + ks * 1024 + q * 512 + r * 16 + hh * 8) = make_uint2(w0, w1);
  }
  __syncthreads();
  char* outb = xhT + (size_t)mt * MT_STRIDE + (size_t)kt * KT_STRIDE;
#pragma unroll
  for (int e = 0; e < 4; ++e) {
    int d = (e * 256 + t) * 16;
    *(uint4*)(outb + d) = *(const uint4*)(st + d);
  }
}

// ====== fast path ======
// R10: m2n2 wave tile (proven R8 decode balance) + A staged to LDS via
// global_load_lds width-16 (compiler can't sink it; loads stay in flight across
// the step). A-tile copied verbatim (linear 16 KB) so fragment addressing is
// identical to R8: frag(i32=wm*2+i, ks) at lane*16 + i*4096 + ks*1024.
// Fragment reads become ds_read_b128 with one base VGPR + immediate offsets
// (cur is compile-time via the 2x-unrolled loop) -> zero per-step A-address VALU.
__global__ __launch_bounds__(NTHREADS, 2)
void ternary_gemm_dc(const char* __restrict__ xhT,
                     const int*  __restrict__ pw,
                     const float* __restrict__ bias,
                     float*       __restrict__ out) {
  __shared__ __align__(16) char Ast[2 * 16384];  // A fp16 tiles, dbuf (verbatim ws layout)
  __shared__ __align__(16) char stg[2 * 2048];   // raw packed B words: 128 rows x int4, dbuf

  const int tid  = threadIdx.x;
  const int lane = tid & 63;
  const int w    = tid >> 6;
  const int wm   = w >> 1, wn = w & 1;
  const int bid  = blockIdx.x;
  const int mt   = bid & 7;           // XCD swizzle: one 2 MiB A-slab per XCD hot in L2
  const int bm   = mt * BM;
  const int bn   = (bid >> 3) * BN;

  // A staging: wave w copies 4 KB chunk w: 4 insts of 16B/lane, linear.
  const char* gAs = xhT + (size_t)mt * MT_STRIDE + w * 4096 + lane * 16;  // + e*1024 + kt*KT
  char* const lA0 = Ast + w * 4096;          // wave-uniform LDS bases
  char* const lA1 = Ast + 16384 + w * 4096;

  // B word staging: thread t -> row t>>1, word-pair t&1 (int2, coalesced global load)
  const int rT = tid >> 1, hT = tid & 1;
  const int2* gB = (const int2*)pw + (size_t)(bn + rT) * (KP / 2) + hT;
  const int stOff = rT * 16 + hT * 8;

  // Consumer rows: fragment j needs words of W-row wn*64 + j*32 + (lane&31)
  int rowOff[2];
#pragma unroll
  for (int j = 0; j < 2; ++j)
    rowOff[j] = (wn * 64 + j * 32 + (lane & 31)) * 16;
  const uint32_t sh = (lane >> 5) * 16;   // quad selects codes 0-7 vs 8-15 of each word

  // A fragment read base: buf/i/ks folded into ds_read immediate offsets
  const char* const aPtr = Ast + wm * 8192 + lane * 16;  // + cur*16384 + i*4096 + ks*1024

  f32x16 acc[2][2];
#pragma unroll
  for (int i = 0; i < 2; ++i)
#pragma unroll
    for (int j = 0; j < 2; ++j) acc[i][j] = (f32x16)(0.f);

  const int NT = K_DIM / BK;   // 128

  auto stageA = [&](char* lbase, int kt) {
    const char* g = gAs + (size_t)kt * KT_STRIDE;
#pragma unroll
    for (int e = 0; e < 4; ++e)
      gload_lds16(g + e * 1024, lbase + e * 1024);
  };

  // ---- prologue: A(tile0)->LDS0 (async); words(tile0)->stg[0]; words(tile1)->regs ----
  stageA(lA0, 0);
  *(int2*)(stg + stOff) = gB[0];
  int2 wcur = gB[2];                                 // tile 1 words
  __syncthreads();   // vmcnt(0)+lgkmcnt(0) drain: A0 + B0 ready

  auto step = [&](int cur, int kt) {
    // Stage next A tile into the other buffer (in flight across this step)
    if (kt + 1 < NT) stageA(cur ? lA0 : lA1, kt + 1);

    // Read this tile's raw words (2 rows x int4); write next tile's words
    uint32_t wr0[4], wr1[4];
    *(uint4*)wr0 = *(const uint4*)(stg + cur * 2048 + rowOff[0]);
    *(uint4*)wr1 = *(const uint4*)(stg + cur * 2048 + rowOff[1]);
    *(int2*)(stg + (cur ^ 1) * 2048 + stOff) = wcur;
    int kn2 = (kt + 2 < NT) ? (kt + 2) : (NT - 1);
    int2 wnxt = gB[kn2 * 2];

    // Compute: A frags from LDS (immediate offsets), decode B in-register
#pragma unroll
    for (int ks = 0; ks < 4; ++ks) {
      half8 a0 = *(const half8*)(aPtr + cur * 16384 + 0 * 4096 + ks * 1024);
      half8 a1 = *(const half8*)(aPtr + cur * 16384 + 1 * 4096 + ks * 1024);
      half8 bf0 = dec_frag(wr0[ks], sh);
      half8 bf1 = dec_frag(wr1[ks], sh);
      acc[0][0] = __builtin_amdgcn_mfma_f32_32x32x16_f16(a0, bf0, acc[0][0], 0, 0, 0);
      acc[0][1] = __builtin_amdgcn_mfma_f32_32x32x16_f16(a0, bf1, acc[0][1], 0, 0, 0);
      acc[1][0] = __builtin_amdgcn_mfma_f32_32x32x16_f16(a1, bf0, acc[1][0], 0, 0, 0);
      acc[1][1] = __builtin_amdgcn_mfma_f32_32x32x16_f16(a1, bf1, acc[1][1], 0, 0, 0);
    }

    __syncthreads();   // drains gload_lds (vmcnt) + ds writes: next buffers ready
    wcur = wnxt;
  };

  for (int kt = 0; kt < NT; kt += 2) {   // 2x unrolled: cur is compile-time 0/1
    step(0, kt);
    step(1, kt + 1);
  }

  // Epilogue: 32x32 C/D (m74/m101): col(n)=lane&31, row(m)=(reg&3)+8*(reg>>2)+4*(lane>>5)
  // fp16 rounding replicated exactly: f16(y) + f16(bias) in half, widen to f32.
#pragma unroll
  for (int j = 0; j < 2; ++j) {
    int n = bn + wn * 64 + j * 32 + (lane & 31);
    __half hb = __float2half_rn(bias[n]);
#pragma unroll
    for (int i = 0; i < 2; ++i) {
      int mbase = bm + wm * 64 + i * 32 + 4 * (lane >> 5);
#pragma unroll
      for (int reg = 0; reg < 16; ++reg) {
        int m = mbase + (reg & 3) + 8 * (reg >> 2);
        __half hy = __float2half_rn(acc[i][j][reg]);
        out[(size_t)m * N_DIM + n] = __half2float(__hadd(hy, hb));
      }
    }
  }
}

// ================= fallback (R4 kernel, known-good): used only if ws too small =================
__device__ __forceinline__ uint32_t unpack_pair16(uint32_t u, int p) {
  uint32_t c0 = (u >> (4 * p)) & 3u;
  uint32_t c1 = (u >> (4 * p + 2)) & 3u;
  uint32_t lo = (c0 & 1u) * 0x3C00u + (c0 >> 1) * 0x0600u;
  uint32_t hi = (c1 & 1u) * 0x3C00u + (c1 >> 1) * 0x0600u;
  return lo | (hi << 16);
}

__global__ __launch_bounds__(NTHREADS, 2)
void ternary_gemm(const float* __restrict__ x,
                  const int*   __restrict__ pw,
                  const float* __restrict__ bias,
                  float*       __restrict__ out) {
  __shared__ __align__(16) char AsB[128 * B_STRIDE];
  __shared__ __align__(16) char BsB[128 * B_STRIDE];

  const int tid  = threadIdx.x;
  const int lane = tid & 63;
  const int w    = tid >> 6;
  const int wm   = w >> 1, wn = w & 1;
  const int bid  = blockIdx.x;
  const int bm   = (bid & 7) * 128;
  const int bn   = (bid >> 3) * 128;

  const int rT = tid >> 1, hT = tid & 1;
  const float* gA = x + (size_t)(bm + rT) * K_DIM + hT * 32;
  char* const  lA = AsB + rT * B_STRIDE + hT * 64;
  const int2* gB = (const int2*)pw + (size_t)(bn + rT) * (KP / 2) + hT;
  char* dBp[4];
#pragma unroll
  for (int h = 0; h < 4; ++h)
    dBp[h] = BsB + rT * B_STRIDE + (hT * 4 + h) * 16;

  int offA[4][2], offB[4][2];
#pragma unroll
  for (int i = 0; i < 4; ++i)
#pragma unroll
    for (int ks = 0; ks < 2; ++ks) {
      int c = ks * 4 + (lane >> 4);
      offA[i][ks] = (wm * 64 + i * 16 + (lane & 15)) * B_STRIDE + c * 16;
      offB[i][ks] = (wn * 64 + i * 16 + (lane & 15)) * B_STRIDE + c * 16;
    }

  f32x4 acc[4][4];
#pragma unroll
  for (int i = 0; i < 4; ++i)
#pragma unroll
    for (int j = 0; j < 4; ++j)
      acc[i][j] = (f32x4){0.f, 0.f, 0.f, 0.f};

  const int NT = K_DIM / BK;
  for (int kt = 0; kt < NT; ++kt) {
    __syncthreads();
    int2 wcur = gB[kt * 2];
    float4 av[8];
#pragma unroll
    for (int v = 0; v < 8; ++v) av[v] = *(const float4*)(gA + kt * BK + v * 4);
    uint32_t d0[8], d1[8];
#pragma unroll
    for (int p = 0; p < 8; ++p) d0[p] = unpack_pair16((uint32_t)wcur.x, p);
#pragma unroll
    for (int p = 0; p < 8; ++p) d1[p] = unpack_pair16((uint32_t)wcur.y, p);
    *(uint4*)dBp[0] = make_uint4(d0[0], d0[1], d0[2], d0[3]);
    *(uint4*)dBp[1] = make_uint4(d0[4], d0[5], d0[6], d0[7]);
    *(uint4*)dBp[2] = make_uint4(d1[0], d1[1], d1[2], d1[3]);
    *(uint4*)dBp[3] = make_uint4(d1[4], d1[5], d1[6], d1[7]);
#pragma unroll
    for (int v = 0; v < 4; ++v) {
      uint4 aw;
      aw.x = cvt2(av[2 * v].x, av[2 * v].y);
      aw.y = cvt2(av[2 * v].z, av[2 * v].w);
      aw.z = cvt2(av[2 * v + 1].x, av[2 * v + 1].y);
      aw.w = cvt2(av[2 * v + 1].z, av[2 * v + 1].w);
      *(uint4*)(lA + v * 16) = aw;
    }
    __syncthreads();
#pragma unroll
    for (int ks = 0; ks < 2; ++ks) {
      half8 af[4], bf[4];
#pragma unroll
      for (int i = 0; i < 4; ++i) af[i] = *(const half8*)(AsB + offA[i][ks]);
#pragma unroll
      for (int j = 0; j < 4; ++j) bf[j] = *(const half8*)(BsB + offB[j][ks]);
#pragma unroll
      for (int i = 0; i < 4; ++i)
#pragma unroll
        for (int j = 0; j < 4; ++j)
          acc[i][j] = __builtin_amdgcn_mfma_f32_16x16x32_f16(af[i], bf[j], acc[i][j], 0, 0, 0);
    }
  }
#pragma unroll
  for (int j = 0; j < 4; ++j) {
    int n = bn + wn * 64 + j * 16 + (lane & 15);
    __half hb = __float2half_rn(bias[n]);
#pragma unroll
    for (int i = 0; i < 4; ++i) {
      int m0 = bm + wm * 64 + i * 16 + (lane >> 4) * 4;
#pragma unroll
      for (int r = 0; r < 4; ++r) {
        __half hy = __float2half_rn(acc[i][j][r]);
        out[(size_t)(m0 + r) * N_DIM + n] = __half2float(__hadd(hy, hb));
      }
    }
  }
}

extern "C" void kernel_launch(void* const* d_in, const int* in_sizes, int n_in,
                              void* d_out, int out_size, void* d_ws, size_t ws_size,
                              hipStream_t stream) {
  (void)in_sizes; (void)n_in; (void)out_size;
  const float* x    = (const float*)d_in[0];
  const int*   pwp  = (const int*)d_in[1];
  const float* bias = (const float*)d_in[2];
  float*       outp = (float*)d_out;

  const size_t need = (size_t)M_DIM * K_DIM * 2;   // 16 MiB fp16 x (transposed)
  if (ws_size >= need) {
    char* xhT = (char*)d_ws;
    cvt_x_t<<<8 * 128, 256, 0, stream>>>(x, xhT);
    dim3 grid((M_DIM / BM) * (N_DIM / BN));        // 512 blocks
    ternary_gemm_dc<<<grid, NTHREADS, 0, stream>>>(xhT, pwp, bias, outp);
  } else {
    dim3 grid((M_DIM / 128) * (N_DIM / 128));      // 512 blocks
    ternary_gemm<<<grid, NTHREADS, 0, stream>>>(x, pwp, bias, outp);
  }
}

// Round 3
// 234.500 us; speedup vs baseline: 1.0764x; 1.0255x over previous
//
#include <hip/hip_runtime.h>
#include <hip/hip_fp16.h>
#include <stdint.h>

// Problem dims (fixed by reference)
// Reference dtypes: x fp16, bias fp16, out fp16 -> harness passes/reads FLOAT32.
// packed_w int32 (8192 x 512), 16 two-bit codes per word, values {0,1,3}.
#define M_DIM 1024
#define N_DIM 8192
#define K_DIM 8192
#define KP    (K_DIM / 16)   // 512 packed int32 words per weight row

#define BM 128
#define BN 128
#define BK 64
#define NTHREADS 256
#define B_STRIDE 144          // fallback kernel only

// Transposed A workspace layout (bytes), built by cvt_x_t:
//   mt(8):2 MiB | kt(128):16 KiB | i32(4):4 KiB | ks(4):1 KiB | q(2):512 | r(32):16
// A-fragment (i32, ks) = contiguous 1 KB at base + lane*16 (lane = q*32+r).
#define MT_STRIDE 2097152
#define KT_STRIDE 16384

typedef _Float16 half8   __attribute__((ext_vector_type(8)));
typedef __fp16   fp16x2  __attribute__((ext_vector_type(2)));
typedef float    f32x4   __attribute__((ext_vector_type(4)));
typedef float    f32x16  __attribute__((ext_vector_type(16)));

__device__ __forceinline__ uint32_t cvt2(float a, float b) {
  fp16x2 p = __builtin_amdgcn_cvt_pkrtz(a, b);   // RTZ exact: values are fp16-representable
  return __builtin_bit_cast(uint32_t, p);
}

// Async global->LDS 16B copy. LDS dest is wave-uniform base + lane*16 (HW rule),
// so the LDS base passed here must be wave-uniform and the global ptr per-lane.
__device__ __forceinline__ void gload_lds16(const char* g, char* l) {
  __builtin_amdgcn_global_load_lds(
      (const __attribute__((address_space(1))) void*)g,
      (__attribute__((address_space(3))) void*)l, 16, 0, 0);
}

// ---- consumer-side half-word ternary decode (verified R8) ----
// word = 16 codes; quad half (sh = quad*16) = 8 codes -> half8 MFMA B-fragment.
// T byte-table [0x00,0x3C,0x06,0x42] = fp16 hi-bytes of {0,1,2,3} (low byte always 0).
__device__ __forceinline__ half8 dec_frag(uint32_t word, uint32_t sh) {
  const uint32_t T = 0x42063C00u;
  uint32_t h  = (word >> sh) & 0xFFFFu;
  uint32_t W  = (h & 0x3333u) | ((h << 14) & 0x33330000u);
  uint32_t c0 = __builtin_amdgcn_perm(0u, W, 0x04040200u);  // W.b0 | W.b2<<8
  uint32_t c1 = __builtin_amdgcn_perm(0u, W, 0x04040301u);  // W.b1 | W.b3<<8
  uint32_t s0 = (c0 * 0x1001u) & 0x03030303u;               // [c0,c1,c2,c3]
  uint32_t s1 = (c1 * 0x1001u) & 0x03030303u;               // [c4,c5,c6,c7]
  uint32_t P0 = __builtin_amdgcn_perm(0u, T, s0);
  uint32_t P1 = __builtin_amdgcn_perm(0u, T, s1);
  uint4 v;
  v.x = __builtin_amdgcn_perm(P0, 0u, 0x05000400u);  // fp16(c0), fp16(c1)
  v.y = __builtin_amdgcn_perm(P0, 0u, 0x07000600u);  // fp16(c2), fp16(c3)
  v.z = __builtin_amdgcn_perm(P1, 0u, 0x05000400u);  // fp16(c4), fp16(c5)
  v.w = __builtin_amdgcn_perm(P1, 0u, 0x07000600u);  // fp16(c6), fp16(c7)
  return __builtin_bit_cast(half8, v);
}

// ---- pre-pass: x f32 -> fp16, transposed-tiled into workspace (R8, verified) ----
__global__ __launch_bounds__(256)
void cvt_x_t(const float* __restrict__ x, char* __restrict__ xhT) {
  __shared__ __align__(16) char st[16384];
  const int b  = blockIdx.x;
  const int mt = b >> 7, kt = b & 127;
  const int t  = threadIdx.x;
#pragma unroll
  for (int p = 0; p < 8; ++p) {
    int f   = t + 256 * p;
    int R   = f >> 4;
    int cc4 = f & 15;
    float4 v = *(const float4*)(x + (size_t)(mt * 128 + R) * K_DIM + kt * 64 + cc4 * 4);
    uint32_t w0 = cvt2(v.x, v.y), w1 = cvt2(v.z, v.w);
    int c8 = cc4 >> 1, hh = cc4 & 1;
    int i32 = R >> 5, r = R & 31, ks = c8 >> 1, q = c8 & 1;
    *(uint2*)(st + i32 * 4096 + ks * 1024 + q * 512 + r * 16 + hh * 8) = make_uint2(w0, w1);
  }
  __syncthreads();
  char* outb = xhT + (size_t)mt * MT_STRIDE + (size_t)kt * KT_STRIDE;
#pragma unroll
  for (int e = 0; e < 4; ++e) {
    int d = (e * 256 + t) * 16;
    *(uint4*)(outb + d) = *(const uint4*)(st + d);
  }
}

// ====== fast path ======
// R11: R10 dataflow (m2n2 wave tile, A via global_load_lds, decode-at-consumer)
// with the T4 counted-vmcnt barrier structure replacing __syncthreads():
//   - A LDS 3-deep (48 KB), staged 2 tiles ahead; B words 3-deep (6 KB).
//   - Step end: s_waitcnt vmcnt(5) lgkmcnt(0) + raw s_barrier. The 5 newest
//     VMEM ops (this step's 4 gload_lds + 1 B-word prefetch) stay IN FLIGHT
//     across the barrier; everything older (= what the next step consumes)
//     is guaranteed complete. Never vmcnt(0) in the main loop.
//   - Safety: prologue + last 2 steps use __syncthreads(); buffer rotation
//     gives every stage >=1 full step of WAR slack (reads of a buffer are
//     lgkm-drained two barriers before it is re-staged).
__global__ __launch_bounds__(NTHREADS, 2)
void ternary_gemm_dc(const char* __restrict__ xhT,
                     const int*  __restrict__ pw,
                     const float* __restrict__ bias,
                     float*       __restrict__ out) {
  __shared__ __align__(16) char Ast[3 * 16384];  // A fp16 tiles, 3-deep (verbatim ws layout)
  __shared__ __align__(16) char stg[3 * 2048];   // raw packed B words: 128 rows x int4, 3-deep

  const int tid  = threadIdx.x;
  const int lane = tid & 63;
  const int w    = tid >> 6;
  const int wm   = w >> 1, wn = w & 1;
  const int bid  = blockIdx.x;
  const int mt   = bid & 7;           // XCD swizzle: one 2 MiB A-slab per XCD hot in L2
  const int bm   = mt * BM;
  const int bn   = (bid >> 3) * BN;

  // A staging: wave w copies 4 KB chunk w: 4 insts of 16B/lane, linear.
  const char* gAs = xhT + (size_t)mt * MT_STRIDE + w * 4096 + lane * 16;  // + e*1024 + kt*KT

  // B word staging: thread t -> row t>>1, word-pair t&1 (int2, coalesced global load)
  const int rT = tid >> 1, hT = tid & 1;
  const int2* gB = (const int2*)pw + (size_t)(bn + rT) * (KP / 2) + hT;
  const int stOff = rT * 16 + hT * 8;

  // Consumer rows: fragment j needs words of W-row wn*64 + j*32 + (lane&31)
  int rowOff[2];
#pragma unroll
  for (int j = 0; j < 2; ++j)
    rowOff[j] = (wn * 64 + j * 32 + (lane & 31)) * 16;
  const uint32_t sh = (lane >> 5) * 16;   // quad selects codes 0-7 vs 8-15 of each word

  // A fragment read base: buf/i/ks folded into ds_read immediate offsets
  const char* const aPtr = Ast + wm * 8192 + lane * 16;  // + buf*16384 + i*4096 + ks*1024

  f32x16 acc[2][2];
#pragma unroll
  for (int i = 0; i < 2; ++i)
#pragma unroll
    for (int j = 0; j < 2; ++j) acc[i][j] = (f32x16)(0.f);

  const int NT = K_DIM / BK;   // 128

  auto stageA = [&](int buf, int kt) {
    const char* g = gAs + (size_t)kt * KT_STRIDE;
    char* lbase = Ast + buf * 16384 + w * 4096;   // wave-uniform LDS base
#pragma unroll
    for (int e = 0; e < 4; ++e)
      gload_lds16(g + e * 1024, lbase + e * 1024);
  };

  // ---- prologue: A(0)->buf0, A(1)->buf1 (async); words(0)->stg0; words(1)->regs ----
  stageA(0, 0);
  stageA(1, 1);
  int2 w0 = gB[0];
  *(int2*)(stg + stOff) = w0;
  int2 wcur = gB[2];                 // tile 1 words
  __syncthreads();                   // full drain ONCE: A0,A1 + B0 ready

  int2 wnxt;
  // step: cur/counted are literal at every call site -> offsets fold, barriers fold.
  auto step = [&](int cur, int kt, bool counted) {
    // Stage tile kt+2 into buffer (cur+2)%3 (in flight across this step's barrier)
    if (kt + 2 < NT) stageA((cur + 2) % 3, kt + 2);

    // Read this tile's raw words (2 rows x int4); write next tile's words
    uint32_t wr0[4], wr1[4];
    *(uint4*)wr0 = *(const uint4*)(stg + cur * 2048 + rowOff[0]);
    *(uint4*)wr1 = *(const uint4*)(stg + cur * 2048 + rowOff[1]);
    *(int2*)(stg + ((cur + 1) % 3) * 2048 + stOff) = wcur;
    int kn2 = (kt + 2 < NT) ? (kt + 2) : (NT - 1);
    wnxt = gB[kn2 * 2];

    // Compute: A frags from LDS (immediate offsets), decode B in-register
#pragma unroll
    for (int ks = 0; ks < 4; ++ks) {
      half8 a0 = *(const half8*)(aPtr + cur * 16384 + 0 * 4096 + ks * 1024);
      half8 a1 = *(const half8*)(aPtr + cur * 16384 + 1 * 4096 + ks * 1024);
      half8 bf0 = dec_frag(wr0[ks], sh);
      half8 bf1 = dec_frag(wr1[ks], sh);
      acc[0][0] = __builtin_amdgcn_mfma_f32_32x32x16_f16(a0, bf0, acc[0][0], 0, 0, 0);
      acc[0][1] = __builtin_amdgcn_mfma_f32_32x32x16_f16(a0, bf1, acc[0][1], 0, 0, 0);
      acc[1][0] = __builtin_amdgcn_mfma_f32_32x32x16_f16(a1, bf0, acc[1][0], 0, 0, 0);
      acc[1][1] = __builtin_amdgcn_mfma_f32_32x32x16_f16(a1, bf1, acc[1][1], 0, 0, 0);
    }

    if (counted) {
      // T4: keep this step's 5 VMEM ops (4 gload_lds + 1 gB) in flight across
      // the barrier; everything older (stage kt+1, prev gB) is forced complete.
      __builtin_amdgcn_sched_barrier(0);
      asm volatile("s_waitcnt vmcnt(5) lgkmcnt(0)" ::: "memory");
      __builtin_amdgcn_s_barrier();
      asm volatile("" ::: "memory");
      __builtin_amdgcn_sched_barrier(0);
    } else {
      __syncthreads();
    }
    wcur = wnxt;
  };

  for (int kt = 0; kt < NT - 2; kt += 3) {   // 42 chunks of 3: cur pattern 0,1,2
    step(0, kt, true);
    step(1, kt + 1, true);
    step(2, kt + 2, true);
  }
  step(0, NT - 2, false);   // tail: full drains, no staging (kt+2 >= NT)
  step(1, NT - 1, false);

  // Epilogue: 32x32 C/D (m74/m101): col(n)=lane&31, row(m)=(reg&3)+8*(reg>>2)+4*(lane>>5)
  // fp16 rounding replicated exactly: f16(y) + f16(bias) in half, widen to f32.
#pragma unroll
  for (int j = 0; j < 2; ++j) {
    int n = bn + wn * 64 + j * 32 + (lane & 31);
    __half hb = __float2half_rn(bias[n]);
#pragma unroll
    for (int i = 0; i < 2; ++i) {
      int mbase = bm + wm * 64 + i * 32 + 4 * (lane >> 5);
#pragma unroll
      for (int reg = 0; reg < 16; ++reg) {
        int m = mbase + (reg & 3) + 8 * (reg >> 2);
        __half hy = __float2half_rn(acc[i][j][reg]);
        out[(size_t)m * N_DIM + n] = __half2float(__hadd(hy, hb));
      }
    }
  }
}

// ================= fallback (R4 kernel, known-good): used only if ws too small =================
__device__ __forceinline__ uint32_t unpack_pair16(uint32_t u, int p) {
  uint32_t c0 = (u >> (4 * p)) & 3u;
  uint32_t c1 = (u >> (4 * p + 2)) & 3u;
  uint32_t lo = (c0 & 1u) * 0x3C00u + (c0 >> 1) * 0x0600u;
  uint32_t hi = (c1 & 1u) * 0x3C00u + (c1 >> 1) * 0x0600u;
  return lo | (hi << 16);
}

__global__ __launch_bounds__(NTHREADS, 2)
void ternary_gemm(const float* __restrict__ x,
                  const int*   __restrict__ pw,
                  const float* __restrict__ bias,
                  float*       __restrict__ out) {
  __shared__ __align__(16) char AsB[128 * B_STRIDE];
  __shared__ __align__(16) char BsB[128 * B_STRIDE];

  const int tid  = threadIdx.x;
  const int lane = tid & 63;
  const int w    = tid >> 6;
  const int wm   = w >> 1, wn = w & 1;
  const int bid  = blockIdx.x;
  const int bm   = (bid & 7) * 128;
  const int bn   = (bid >> 3) * 128;

  const int rT = tid >> 1, hT = tid & 1;
  const float* gA = x + (size_t)(bm + rT) * K_DIM + hT * 32;
  char* const  lA = AsB + rT * B_STRIDE + hT * 64;
  const int2* gB = (const int2*)pw + (size_t)(bn + rT) * (KP / 2) + hT;
  char* dBp[4];
#pragma unroll
  for (int h = 0; h < 4; ++h)
    dBp[h] = BsB + rT * B_STRIDE + (hT * 4 + h) * 16;

  int offA[4][2], offB[4][2];
#pragma unroll
  for (int i = 0; i < 4; ++i)
#pragma unroll
    for (int ks = 0; ks < 2; ++ks) {
      int c = ks * 4 + (lane >> 4);
      offA[i][ks] = (wm * 64 + i * 16 + (lane & 15)) * B_STRIDE + c * 16;
      offB[i][ks] = (wn * 64 + i * 16 + (lane & 15)) * B_STRIDE + c * 16;
    }

  f32x4 acc[4][4];
#pragma unroll
  for (int i = 0; i < 4; ++i)
#pragma unroll
    for (int j = 0; j < 4; ++j)
      acc[i][j] = (f32x4){0.f, 0.f, 0.f, 0.f};

  const int NT = K_DIM / BK;
  for (int kt = 0; kt < NT; ++kt) {
    __syncthreads();
    int2 wcur = gB[kt * 2];
    float4 av[8];
#pragma unroll
    for (int v = 0; v < 8; ++v) av[v] = *(const float4*)(gA + kt * BK + v * 4);
    uint32_t d0[8], d1[8];
#pragma unroll
    for (int p = 0; p < 8; ++p) d0[p] = unpack_pair16((uint32_t)wcur.x, p);
#pragma unroll
    for (int p = 0; p < 8; ++p) d1[p] = unpack_pair16((uint32_t)wcur.y, p);
    *(uint4*)dBp[0] = make_uint4(d0[0], d0[1], d0[2], d0[3]);
    *(uint4*)dBp[1] = make_uint4(d0[4], d0[5], d0[6], d0[7]);
    *(uint4*)dBp[2] = make_uint4(d1[0], d1[1], d1[2], d1[3]);
    *(uint4*)dBp[3] = make_uint4(d1[4], d1[5], d1[6], d1[7]);
#pragma unroll
    for (int v = 0; v < 4; ++v) {
      uint4 aw;
      aw.x = cvt2(av[2 * v].x, av[2 * v].y);
      aw.y = cvt2(av[2 * v].z, av[2 * v].w);
      aw.z = cvt2(av[2 * v + 1].x, av[2 * v + 1].y);
      aw.w = cvt2(av[2 * v + 1].z, av[2 * v + 1].w);
      *(uint4*)(lA + v * 16) = aw;
    }
    __syncthreads();
#pragma unroll
    for (int ks = 0; ks < 2; ++ks) {
      half8 af[4], bf[4];
#pragma unroll
      for (int i = 0; i < 4; ++i) af[i] = *(const half8*)(AsB + offA[i][ks]);
#pragma unroll
      for (int j = 0; j < 4; ++j) bf[j] = *(const half8*)(BsB + offB[j][ks]);
#pragma unroll
      for (int i = 0; i < 4; ++i)
#pragma unroll
        for (int j = 0; j < 4; ++j)
          acc[i][j] = __builtin_amdgcn_mfma_f32_16x16x32_f16(af[i], bf[j], acc[i][j], 0, 0, 0);
    }
  }
#pragma unroll
  for (int j = 0; j < 4; ++j) {
    int n = bn + wn * 64 + j * 16 + (lane & 15);
    __half hb = __float2half_rn(bias[n]);
#pragma unroll
    for (int i = 0; i < 4; ++i) {
      int m0 = bm + wm * 64 + i * 16 + (lane >> 4) * 4;
#pragma unroll
      for (int r = 0; r < 4; ++r) {
        __half hy = __float2half_rn(acc[i][j][r]);
        out[(size_t)(m0 + r) * N_DIM + n] = __half2float(__hadd(hy, hb));
      }
    }
  }
}

extern "C" void kernel_launch(void* const* d_in, const int* in_sizes, int n_in,
                              void* d_out, int out_size, void* d_ws, size_t ws_size,
                              hipStream_t stream) {
  (void)in_sizes; (void)n_in; (void)out_size;
  const float* x    = (const float*)d_in[0];
  const int*   pwp  = (const int*)d_in[1];
  const float* bias = (const float*)d_in[2];
  float*       outp = (float*)d_out;

  const size_t need = (size_t)M_DIM * K_DIM * 2;   // 16 MiB fp16 x (transposed)
  if (ws_size >= need) {
    char* xhT = (char*)d_ws;
    cvt_x_t<<<8 * 128, 256, 0, stream>>>(x, xhT);
    dim3 grid((M_DIM / BM) * (N_DIM / BN));        // 512 blocks
    ternary_gemm_dc<<<grid, NTHREADS, 0, stream>>>(xhT, pwp, bias, outp);
  } else {
    dim3 grid((M_DIM / 128) * (N_DIM / 128));      // 512 blocks
    ternary_gemm<<<grid, NTHREADS, 0, stream>>>(x, pwp, bias, outp);
  }
}